// Round 9
// baseline (1013.799 us; speedup 1.0000x reference)
//
#include <hip/hip_runtime.h>
#include <hip/hip_bf16.h>
#include <cstdio>

// GCNTox21 — round 20. r19 post-mortem: neutral. scatter_k is the hidden
// ~180-200us monster: two 4B random writes per edge = 2 RMW lines/edge
// (~205MB). Fix:
//  (1) packed scatter: one int2{src,eid} write per edge -> 1 line/edge
//      (~105MB); conv reads 32B contiguous scalar per 4-edge group.
//  (2) e16 pipeline back to r17 style: edge_emb_k gathers ea[eid] (random
//      READS, L3-resident, latency hidden by 25.6M threads) and writes e16s
//      in CSR order coalesced; conv reads e16s SEQUENTIALLY (undoes r19's
//      +60MB/conv gather).
// Keeps: edge-balanced conv units, node_emb2, BN-in-proj, matvec2, pool_bn.

#define N_NODES 100000
#define N_EDGES 1600000
#define NUM_GRAPHS 4096

typedef unsigned short u16;
typedef unsigned int u32;
typedef _Float16 h2 __attribute__((ext_vector_type(2)));

#if defined(__has_builtin)
#if __has_builtin(__builtin_amdgcn_fdot2)
#define DOT2(a, b, c) __builtin_amdgcn_fdot2((a), (b), (c), false)
#endif
#endif
#ifndef DOT2
#define DOT2(a, b, c) ((c) + (float)(a).x * (float)(b).x + (float)(a).y * (float)(b).y)
#endif

__device__ __forceinline__ float b2f(u16 u) { union { u32 i; float f; } c; c.i = ((u32)u) << 16; return c.f; }
__device__ __forceinline__ float b2f_lo(u32 u) { union { u32 i; float f; } c; c.i = u << 16; return c.f; }
__device__ __forceinline__ float b2f_hi(u32 u) { union { u32 i; float f; } c; c.i = u & 0xffff0000u; return c.f; }
__device__ __forceinline__ u16 f2b(float f) {
    __hip_bfloat16 h = __float2bfloat16(f);
    return *reinterpret_cast<u16*>(&h);
}

template <int CPL>
__device__ __forceinline__ void ld_bf16(const u16* base, float out[CPL]) {
    if constexpr (CPL == 1) {
        out[0] = b2f(*base);
    } else {
        u32 v = *(const u32*)base;
        out[0] = b2f_lo(v); out[1] = b2f_hi(v);
    }
}
template <int CPL>
__device__ __forceinline__ void ld_f32(const float* base, float out[CPL]) {
    if constexpr (CPL == 1) {
        out[0] = *base;
    } else {
        float2 v = *(const float2*)base;
        out[0] = v.x; out[1] = v.y;
    }
}

// ---------------- CSR build ----------------
__global__ __launch_bounds__(256) void hist_k(const int* __restrict__ dst, int* __restrict__ hist) {
    int e = blockIdx.x * 256 + threadIdx.x;
    if (e < N_EDGES) atomicAdd(&hist[dst[e]], 1);
}

__global__ __launch_bounds__(256) void scan_part_k(const int* __restrict__ hist,
        int* __restrict__ excl, int* __restrict__ bsum) {
    __shared__ int sm[256];
    int t = threadIdx.x, b = blockIdx.x;
    int base = b * 1024 + t * 4;
    int v0 = (base + 0 < N_NODES) ? hist[base + 0] : 0;
    int v1 = (base + 1 < N_NODES) ? hist[base + 1] : 0;
    int v2 = (base + 2 < N_NODES) ? hist[base + 2] : 0;
    int v3 = (base + 3 < N_NODES) ? hist[base + 3] : 0;
    int tsum = v0 + v1 + v2 + v3;
    sm[t] = tsum;
    __syncthreads();
    for (int o = 1; o < 256; o <<= 1) {
        int x = (t >= o) ? sm[t - o] : 0;
        __syncthreads();
        sm[t] += x;
        __syncthreads();
    }
    int texcl = sm[t] - tsum;
    if (base + 0 < N_NODES) excl[base + 0] = texcl;
    if (base + 1 < N_NODES) excl[base + 1] = texcl + v0;
    if (base + 2 < N_NODES) excl[base + 2] = texcl + v0 + v1;
    if (base + 3 < N_NODES) excl[base + 3] = texcl + v0 + v1 + v2;
    if (t == 255) bsum[b] = sm[255];
}

__global__ __launch_bounds__(256) void scan_top_k(int* __restrict__ bsum, int* __restrict__ boff,
        int nb, int* __restrict__ row_ptr_last) {
    __shared__ int sm[256];
    int t = threadIdx.x;
    int v = (t < nb) ? bsum[t] : 0;
    sm[t] = v;
    __syncthreads();
    for (int o = 1; o < 256; o <<= 1) {
        int x = (t >= o) ? sm[t - o] : 0;
        __syncthreads();
        sm[t] += x;
        __syncthreads();
    }
    if (t < nb) boff[t] = sm[t] - v;
    if (t == 0) *row_ptr_last = sm[255];
}

__global__ __launch_bounds__(256) void scan_add_k(int* __restrict__ excl, const int* __restrict__ boff,
        int* __restrict__ row_ptr, int* __restrict__ cursor) {
    int i = blockIdx.x * 256 + threadIdx.x;
    if (i >= N_NODES) return;
    int s = excl[i] + boff[i >> 10];
    row_ptr[i] = s;
    cursor[i] = s;
}

// packed scatter: ONE int2{src,eid} random write per edge (1 RMW line)
__global__ __launch_bounds__(256) void scatter_k(const int* __restrict__ src, const int* __restrict__ dst,
        int* __restrict__ cursor, int2* __restrict__ epk) {
    int e = blockIdx.x * 256 + threadIdx.x;
    if (e < N_EDGES) {
        int p = atomicAdd(&cursor[dst[e]], 1);
        int2 q; q.x = src[e]; q.y = e;
        epk[p] = q;
    }
}

// edge-balanced node partition: sn[u] = lower_bound(row_ptr, 64*u)
__global__ __launch_bounds__(256) void ubound_k(const int* __restrict__ row_ptr, int* __restrict__ sn) {
    int u = blockIdx.x * 256 + threadIdx.x;
    if (u > 25000) return;
    if (u == 25000) { sn[u] = N_NODES; return; }
    int target = u * 64;
    int lo = 0, hi = N_NODES;
    while (lo < hi) {
        int mid = (lo + hi) >> 1;
        if (row_ptr[mid] >= target) hi = mid; else lo = mid + 1;
    }
    sn[u] = lo;
}

// ---------------- edge embedding: CSR-order output, ea gathered by eid ----
__global__ __launch_bounds__(256) void edge_emb_k(const float* __restrict__ ea,
        const float* __restrict__ We, const float* __restrict__ be,
        const int2* __restrict__ epk, _Float16* __restrict__ e16s) {
    int idx = blockIdx.x * 256 + threadIdx.x;       // E*16 threads exactly
    int p = idx >> 4, k = idx & 15;
    int e = epk[p].y;
    float4 a0 = *(const float4*)(ea + (size_t)e * 8);
    float4 a1 = *(const float4*)(ea + (size_t)e * 8 + 4);
    float acc = be[k];
    acc += a0.x * We[0 * 16 + k];
    acc += a0.y * We[1 * 16 + k];
    acc += a0.z * We[2 * 16 + k];
    acc += a0.w * We[3 * 16 + k];
    acc += a1.x * We[4 * 16 + k];
    acc += a1.y * We[5 * 16 + k];
    acc += a1.z * We[6 * 16 + k];
    acc += a1.w * We[7 * 16 + k];
    e16s[(size_t)idx] = (_Float16)fmaxf(acc, 0.f);
}

// ---------------- node embedding: proj-pattern ----------------
__global__ __launch_bounds__(256) void node_emb2_k(const float* __restrict__ x,
        const float* __restrict__ Wn, const float* __restrict__ bn_, float* __restrict__ h) {
    constexpr int C = 64, F = 32, TILE = 64;     // 4 node groups x 16 nodes
    __shared__ float xs[TILE * F];               // 8 KB
    const int t = threadIdx.x;
    const int grp = t / C;
    const int c = t % C;
    float w[F];
#pragma unroll
    for (int k = 0; k < F; ++k) w[k] = Wn[(size_t)k * 64 + c];
    const float bias = bn_[c];
    const float4* xsrc = (const float4*)x;
    float4* xs4 = (float4*)xs;

    for (int v0 = blockIdx.x * TILE; v0 < N_NODES; v0 += gridDim.x * TILE) {
        __syncthreads();
        for (int i = t; i < TILE * F / 4; i += 256) {   // 512 float4, 2/thread
            int vv = v0 + (i * 4) / F;
            float4 val;
            if (vv < N_NODES) val = xsrc[(size_t)v0 * (F / 4) + i];
            else { val.x = val.y = val.z = val.w = 0.f; }
            xs4[i] = val;
        }
        __syncthreads();
        const int base = grp * 16;
        const int nmax = (N_NODES - v0 - base >= 16) ? 16
                        : (N_NODES - v0 - base > 0 ? N_NODES - v0 - base : 0);
        for (int n = 0; n < nmax; ++n) {
            const int v = v0 + base + n;
            const float4* xr4 = (const float4*)&xs[(base + n) * F];
            float a0 = bias, a1 = 0.f, a2 = 0.f, a3 = 0.f;
#pragma unroll
            for (int k4 = 0; k4 < F / 4; ++k4) {
                float4 hv = xr4[k4];
                a0 += hv.x * w[4 * k4 + 0];
                a1 += hv.y * w[4 * k4 + 1];
                a2 += hv.z * w[4 * k4 + 2];
                a3 += hv.w * w[4 * k4 + 3];
            }
            h[(size_t)v * 64 + c] = fmaxf((a0 + a1) + (a2 + a3), 0.f);
        }
    }
}

// ---------------- projections: Pd fp32, Ps bf16; optional fused BN+relu ----
template <int F, int H, bool BN>
__global__ __launch_bounds__(256) void proj_k(const float* __restrict__ h,
        const float* __restrict__ Wa, const float* __restrict__ ba,
        const float* __restrict__ stats, const float* __restrict__ g, const float* __restrict__ beta,
        float* __restrict__ Pd, u16* __restrict__ Ps) {
    constexpr int C2 = 2 * H;
    constexpr int NPB = 256 / C2;
    constexpr int TILE = 16 * NPB;
    __shared__ float hs[TILE][F];
    __shared__ float sc[BN ? F : 1];
    __shared__ float shv[BN ? F : 1];
    const int t = threadIdx.x;
    if constexpr (BN) {
        if (t < F) {
            const float invN = 1.0f / (float)N_NODES;
            float mu = stats[t] * invN;
            float ex2 = stats[F + t] * invN;
            float var = fmaxf(ex2 - mu * mu, 0.f);
            float rs = rsqrtf(var + 1e-5f);
            float scale = rs * g[t];
            sc[t] = scale;
            shv[t] = beta[t] - mu * scale;
        }
    }
    const int grp = t / C2;
    const int c = t % C2;
    const bool is_src = (c >= H);
    const int cc = is_src ? (c - H) : c;
    float w[F];
    const float* wcol = Wa + (size_t)(is_src ? F : 0) * H + cc;
#pragma unroll
    for (int k = 0; k < F; ++k) w[k] = wcol[(size_t)k * H];
    const float bias = is_src ? 0.f : ba[cc];

    for (int v0 = blockIdx.x * TILE; v0 < N_NODES; v0 += gridDim.x * TILE) {
        __syncthreads();
        for (int i = t; i < TILE * F; i += 256) {
            int vv = v0 + i / F;
            float val = (vv < N_NODES) ? h[(size_t)vv * F + (i % F)] : 0.f;
            if constexpr (BN) val = fmaxf(val * sc[i % F] + shv[i % F], 0.f);
            hs[i / F][i % F] = val;
        }
        __syncthreads();
        const int base = grp * 16;
        const int nmax = (N_NODES - v0 - base >= 16) ? 16
                        : (N_NODES - v0 - base > 0 ? N_NODES - v0 - base : 0);
#pragma unroll 2
        for (int n = 0; n < nmax; ++n) {
            const int v = v0 + base + n;
            const float4* hr4 = (const float4*)hs[base + n];
            float a0 = bias, a1 = 0.f, a2 = 0.f, a3 = 0.f;
#pragma unroll
            for (int k4 = 0; k4 < F / 4; ++k4) {
                float4 hv = hr4[k4];
                a0 += hv.x * w[4 * k4 + 0];
                a1 += hv.y * w[4 * k4 + 1];
                a2 += hv.z * w[4 * k4 + 2];
                a3 += hv.w * w[4 * k4 + 3];
            }
            float acc = (a0 + a1) + (a2 + a3);
            if (is_src) Ps[(size_t)v * H + cc] = f2b(acc);
            else        Pd[(size_t)v * H + cc] = acc;
        }
    }
}

// ---------------- fused conv: edge-balanced units, sequential e16s ---------
template <int H>
__global__ __launch_bounds__(256) void conv_k(
        const int* __restrict__ sn, const int* __restrict__ row_ptr,
        const int2* __restrict__ epk, const _Float16* __restrict__ e16s,
        float* __restrict__ Pd, const u16* __restrict__ Ps,
        const float* __restrict__ Wae) {
    constexpr int SL = (H >= 64) ? 64 : 32;   // lanes per node
    constexpr int NPW = 64 / SL;              // units per wave
    constexpr int CPL = H / SL;               // channels per lane
    const int wave = threadIdx.x >> 6, lane = threadIdx.x & 63;
    const int sub = lane / SL;
    const int sl = lane % SL;
    const int c0 = sl * CPL;
    h2 w2h[8][CPL];
#pragma unroll
    for (int k2 = 0; k2 < 8; ++k2)
#pragma unroll
        for (int j = 0; j < CPL; ++j) {
            h2 t;
            t.x = (_Float16)Wae[(2 * k2) * H + c0 + j];
            t.y = (_Float16)Wae[(2 * k2 + 1) * H + c0 + j];
            w2h[k2][j] = t;
        }

    const int uid = (blockIdx.x * 4 + wave) * NPW + sub;
    const int vbeg = sn[uid], vend = sn[uid + 1];

    for (int v = vbeg; v < vend; ++v) {
        const int vv = (SL == 64) ? __builtin_amdgcn_readfirstlane(v) : v;
        float pd[CPL], acc[CPL];
        ld_f32<CPL>(&Pd[(size_t)vv * H + c0], pd);
#pragma unroll
        for (int j = 0; j < CPL; ++j) acc[j] = 0.f;
        const int p0 = row_ptr[vv], p1 = row_ptr[vv + 1];
        const int deg = p1 - p0;

        auto edge = [&](uint4 ra, uint4 rb, const float ps[CPL]) {
            union { u32 u; h2 h; } cv;
            h2 ev[8];
            cv.u = ra.x; ev[0] = cv.h; cv.u = ra.y; ev[1] = cv.h;
            cv.u = ra.z; ev[2] = cv.h; cv.u = ra.w; ev[3] = cv.h;
            cv.u = rb.x; ev[4] = cv.h; cv.u = rb.y; ev[5] = cv.h;
            cv.u = rb.z; ev[6] = cv.h; cv.u = rb.w; ev[7] = cv.h;
            float z[CPL];
#pragma unroll
            for (int j = 0; j < CPL; ++j) z[j] = pd[j] + ps[j];
#pragma unroll
            for (int k2 = 0; k2 < 8; ++k2)
#pragma unroll
                for (int j = 0; j < CPL; ++j) z[j] = DOT2(ev[k2], w2h[k2][j], z[j]);
#pragma unroll
            for (int j = 0; j < CPL; ++j) acc[j] += fmaxf(z[j], 0.f);
        };

        int p = p0;
        for (; p + 3 < p1; p += 4) {
            int2 q0 = epk[p], q1 = epk[p + 1], q2 = epk[p + 2], q3 = epk[p + 3];
            const uint4* e0 = (const uint4*)(e16s + (size_t)p * 16);
            uint4 a0 = e0[0], a1 = e0[1];
            uint4 b0 = e0[2], b1 = e0[3];
            uint4 g0 = e0[4], g1 = e0[5];
            uint4 d0 = e0[6], d1 = e0[7];
            float ps0[CPL], ps1[CPL], ps2[CPL], ps3[CPL];
            ld_bf16<CPL>(&Ps[(size_t)q0.x * H + c0], ps0);
            ld_bf16<CPL>(&Ps[(size_t)q1.x * H + c0], ps1);
            ld_bf16<CPL>(&Ps[(size_t)q2.x * H + c0], ps2);
            ld_bf16<CPL>(&Ps[(size_t)q3.x * H + c0], ps3);
            edge(a0, a1, ps0);
            edge(b0, b1, ps1);
            edge(g0, g1, ps2);
            edge(d0, d1, ps3);
        }
        for (; p < p1; ++p) {
            int2 q0 = epk[p];
            const uint4* e0 = (const uint4*)(e16s + (size_t)p * 16);
            uint4 a0 = e0[0], a1 = e0[1];
            float ps0[CPL];
            ld_bf16<CPL>(&Ps[(size_t)q0.x * H + c0], ps0);
            edge(a0, a1, ps0);
        }

        const float invd = (deg > 0) ? 1.f / (float)deg : 0.f;
        if constexpr (CPL == 2) {
            float2 o; o.x = acc[0] * invd; o.y = acc[1] * invd;
            *(float2*)&Pd[(size_t)vv * H + c0] = o;
        } else {
            Pd[(size_t)vv * H + c0] = acc[0] * invd;
        }
    }
}

// ---------------- y = m @ Wb + bb (deg>0 mask) + fused BN stats ----------
template <int H, int Fo>
__global__ __launch_bounds__(256) void matvec2_k(const float* __restrict__ m,
        const int* __restrict__ row_ptr,
        const float* __restrict__ Wb, const float* __restrict__ bb,
        float* __restrict__ y, float* __restrict__ stats) {
    constexpr int FoC = (Fo < 32) ? Fo : 32;  // channels per wave: 32/32/16
    constexpr int CG = Fo / FoC;              // channel groups: 2/1/1
    constexpr int NPW = 32 / FoC;             // node subs per half-wave: 1/1/2
    constexpr int NG = 4 / CG;                // node groups (waves): 2/4/4
    constexpr int SLOTS = NG * NPW;           // node slots per pass: 2/4/8
    constexpr int KH = H / 2;                 // k per lane: 64/32/16
    constexpr int TILE = 4096 / H;            // nodes per tile: 32/64/128
    constexpr int J = TILE / SLOTS;           // 16 for all shapes

    __shared__ float hs[TILE * H];            // 16 KB
    __shared__ int ptile[TILE + 1];
    __shared__ float sh[2 * Fo];

    const int t = threadIdx.x;
    const int wave = t >> 6, lane = t & 63;
    const int kh = lane >> 5;
    const int r = lane & 31;
    const int c_lo = r % FoC;
    const int s = r / FoC;
    const int cg = wave % CG;
    const int ng = wave / CG;
    const int c = cg * FoC + c_lo;
    const int slot = ng * NPW + s;

    for (int i = t; i < 2 * Fo; i += 256) sh[i] = 0.f;

    float w[KH];
#pragma unroll
    for (int k = 0; k < KH; ++k) w[k] = Wb[(size_t)(kh * KH + k) * Fo + c];
    const float bias = bb[c];
    float s1 = 0.f, s2 = 0.f;

    const float4* msrc = (const float4*)m;
    float4* hs4 = (float4*)hs;

    for (int v0 = blockIdx.x * TILE; v0 < N_NODES; v0 += gridDim.x * TILE) {
        __syncthreads();
#pragma unroll
        for (int q = t; q < 1024; q += 256) {
            int node = (q * 4) / H;
            float4 val;
            if (v0 + node < N_NODES) val = msrc[(size_t)v0 * (H / 4) + q];
            else { val.x = val.y = val.z = val.w = 0.f; }
            hs4[q] = val;
        }
        for (int i = t; i <= TILE; i += 256) {
            int v = v0 + i;
            ptile[i] = row_ptr[v < N_NODES ? v : N_NODES];
        }
        __syncthreads();

        for (int j = 0; j < J; ++j) {
            const int n = slot + j * SLOTS;
            const int v = v0 + n;
            const float4* hr4 = (const float4*)&hs[n * H + kh * KH];
            float a0 = 0.f, a1 = 0.f, a2 = 0.f, a3 = 0.f;
#pragma unroll
            for (int k4 = 0; k4 < KH / 4; ++k4) {
                float4 hv = hr4[k4];
                a0 += hv.x * w[4 * k4 + 0];
                a1 += hv.y * w[4 * k4 + 1];
                a2 += hv.z * w[4 * k4 + 2];
                a3 += hv.w * w[4 * k4 + 3];
            }
            float half = (a0 + a1) + (a2 + a3);
            float total = half + __shfl_xor(half, 32) + bias;
            if (kh == 0 && v < N_NODES) {
                const int deg = ptile[n + 1] - ptile[n];
                float val = (deg > 0) ? total : 0.f;
                y[(size_t)v * Fo + c] = val;
                s1 += val; s2 += val * val;
            }
        }
    }

    __syncthreads();
    if (kh == 0) {
        atomicAdd(&sh[c], s1);
        atomicAdd(&sh[Fo + c], s2);
    }
    __syncthreads();
    if (t < 2 * Fo) atomicAdd(&stats[t], sh[t]);
}

// ---------------- pooling (fused BN3+relu) & head ----------------
__global__ __launch_bounds__(256) void pool_bn_k(const float* __restrict__ y,
        const float* __restrict__ stats, const float* __restrict__ g, const float* __restrict__ beta,
        const int* __restrict__ batch, float* __restrict__ pool, int* __restrict__ gcnt) {
    int idx = blockIdx.x * 256 + threadIdx.x;
    if (idx >= N_NODES * 16) return;
    int v = idx >> 4, c = idx & 15;
    const float invN = 1.0f / (float)N_NODES;
    float mu = stats[c] * invN;
    float ex2 = stats[16 + c] * invN;
    float var = fmaxf(ex2 - mu * mu, 0.f);
    float rs = rsqrtf(var + 1e-5f);
    float val = fmaxf((y[idx] - mu) * rs * g[c] + beta[c], 0.f);
    int b = batch[v];
    atomicAdd(&pool[b * 16 + c], val);
    if (c == 0) atomicAdd(&gcnt[b], 1);
}

__global__ __launch_bounds__(256) void out_k(const float* __restrict__ pool,
        const int* __restrict__ gcnt, const float* __restrict__ Wfc,
        const float* __restrict__ bfc, float* __restrict__ out) {
    int idx = blockIdx.x * 256 + threadIdx.x;
    if (idx >= NUM_GRAPHS * 12) return;
    int g = idx / 12, o = idx % 12;
    int cnt = gcnt[g];
    float inv = 1.0f / (float)(cnt > 0 ? cnt : 1);
    float acc = bfc[o];
#pragma unroll
    for (int k = 0; k < 16; ++k) acc += pool[g * 16 + k] * inv * Wfc[k * 12 + o];
    out[idx] = 1.0f / (1.0f + expf(-acc));
}

extern "C" void kernel_launch(void* const* d_in, const int* in_sizes, int n_in,
                              void* d_out, int out_size, void* d_ws, size_t ws_size,
                              hipStream_t stream) {
    const size_t N = N_NODES, E = N_EDGES, G = NUM_GRAPHS;
    const float* x = (const float*)d_in[0];
    const float* ea = (const float*)d_in[1];
    const int* ei = (const int*)d_in[2];
    const int* srcv = ei;
    const int* dstv = ei + E;
    const int* batch = (const int*)d_in[3];
    const float* Wn = (const float*)d_in[5];  const float* bn_ = (const float*)d_in[6];
    const float* We = (const float*)d_in[7];  const float* be_ = (const float*)d_in[8];
    const float* W1a = (const float*)d_in[9]; const float* b1a = (const float*)d_in[10];
    const float* W1b = (const float*)d_in[11]; const float* b1b = (const float*)d_in[12];
    const float* W2a = (const float*)d_in[13]; const float* b2a = (const float*)d_in[14];
    const float* W2b = (const float*)d_in[15]; const float* b2b = (const float*)d_in[16];
    const float* W3a = (const float*)d_in[17]; const float* b3a = (const float*)d_in[18];
    const float* W3b = (const float*)d_in[19]; const float* b3b = (const float*)d_in[20];
    const float* g1 = (const float*)d_in[21]; const float* be1 = (const float*)d_in[22];
    const float* g2 = (const float*)d_in[23]; const float* be2 = (const float*)d_in[24];
    const float* g3 = (const float*)d_in[25]; const float* be3 = (const float*)d_in[26];
    const float* Wfc = (const float*)d_in[27]; const float* bfc = (const float*)d_in[28];

    char* base = (char*)d_ws;
    size_t off = 0;
    auto take = [&](size_t bytes) { size_t o = off; off += (bytes + 255) & ~(size_t)255; return o; };
    int* hist = (int*)(base + take(N * 4));
    int* cursor = (int*)(base + take(N * 4));
    int* row_ptr = (int*)(base + take((N + 1) * 4));
    int* bsum = (int*)(base + take(256 * 4));
    int* boff = (int*)(base + take(256 * 4));
    int* sn = (int*)(base + take(25001 * 4));
    int2* epk = (int2*)(base + take(E * 8));
    float* hbuf = (float*)(base + take(N * 64 * 4));
    float* Pd = (float*)(base + take(N * 128 * 4));
    u16* Ps = (u16*)(base + take(N * 128 * 2));
    _Float16* e16s = (_Float16*)(base + take(E * 16 * 2));
    float* stats = (float*)(base + take(256 * 4));
    float* pool = (float*)(base + take(G * 16 * 4));
    int* gcnt = (int*)(base + take(G * 4));
    if (off > ws_size) {
        fprintf(stderr, "kernel_launch: ws too small: need %zu have %zu\n", off, ws_size);
        return;
    }

    const int NB = (N_NODES + 1023) / 1024;

    // CSR build (packed int2 scatter: 1 RMW line per edge)
    hipMemsetAsync(hist, 0, N * 4, stream);
    hist_k<<<dim3((E + 255) / 256), dim3(256), 0, stream>>>(dstv, hist);
    scan_part_k<<<dim3(NB), dim3(256), 0, stream>>>(hist, cursor, bsum);
    scan_top_k<<<dim3(1), dim3(256), 0, stream>>>(bsum, boff, NB, &row_ptr[N_NODES]);
    scan_add_k<<<dim3((N + 255) / 256), dim3(256), 0, stream>>>(cursor, boff, row_ptr, cursor);
    scatter_k<<<dim3((E + 255) / 256), dim3(256), 0, stream>>>(srcv, dstv, cursor, epk);
    ubound_k<<<dim3((25001 + 255) / 256), dim3(256), 0, stream>>>(row_ptr, sn);

    // embeddings: e16s in CSR order (coalesced write, random L3 ea reads)
    edge_emb_k<<<dim3(E * 16 / 256), dim3(256), 0, stream>>>(ea, We, be_, epk, e16s);
    node_emb2_k<<<dim3(1563), dim3(256), 0, stream>>>(x, Wn, bn_, hbuf);

    // conv1: F=64, H=128, Fo=64  (no BN on h)
    proj_k<64, 128, false><<<dim3(6250), dim3(256), 0, stream>>>(hbuf, W1a, b1a, nullptr, nullptr, nullptr, Pd, Ps);
    conv_k<128><<<dim3(6250), dim3(256), 0, stream>>>(sn, row_ptr, epk, e16s, Pd, Ps, W1a + 128 * 128);
    hipMemsetAsync(stats, 0, 256 * 4, stream);
    matvec2_k<128, 64><<<dim3(1024), dim3(256), 0, stream>>>(Pd, row_ptr, W1b, b1b, hbuf, stats);

    // conv2: F=64, H=64, Fo=32  (BN1 fused into proj staging)
    proj_k<64, 64, true><<<dim3(3125), dim3(256), 0, stream>>>(hbuf, W2a, b2a, stats, g1, be1, Pd, Ps);
    conv_k<64><<<dim3(6250), dim3(256), 0, stream>>>(sn, row_ptr, epk, e16s, Pd, Ps, W2a + 128 * 64);
    hipMemsetAsync(stats, 0, 256 * 4, stream);
    matvec2_k<64, 32><<<dim3(1024), dim3(256), 0, stream>>>(Pd, row_ptr, W2b, b2b, hbuf, stats);

    // conv3: F=32, H=32, Fo=16  (BN2 fused into proj staging)
    proj_k<32, 32, true><<<dim3(1563), dim3(256), 0, stream>>>(hbuf, W3a, b3a, stats, g2, be2, Pd, Ps);
    conv_k<32><<<dim3(3125), dim3(256), 0, stream>>>(sn, row_ptr, epk, e16s, Pd, Ps, W3a + 64 * 32);
    hipMemsetAsync(stats, 0, 256 * 4, stream);
    matvec2_k<32, 16><<<dim3(1024), dim3(256), 0, stream>>>(Pd, row_ptr, W3b, b3b, hbuf, stats);

    // pool (BN3+relu fused) + head
    hipMemsetAsync(pool, 0, G * 16 * 4, stream);
    hipMemsetAsync(gcnt, 0, G * 4, stream);
    pool_bn_k<<<dim3((N * 16 + 255) / 256), dim3(256), 0, stream>>>(hbuf, stats, g3, be3, batch, pool, gcnt);
    out_k<<<dim3((G * 12 + 255) / 256), dim3(256), 0, stream>>>(pool, gcnt, Wfc, bfc, (float*)d_out);
}

// Round 10
// 942.743 us; speedup vs baseline: 1.0754x; 1.0754x over previous
//
#include <hip/hip_runtime.h>
#include <hip/hip_bf16.h>
#include <cstdio>

// GCNTox21 — round 21. r20 counters: scatter_k = 132us, VALUBusy 0.35%,
// WRITE_SIZE 100MB = 1.6M x 64B -> every 8B random write dirties a full
// line; cross-XCD L2s never merge. Fix: two-pass bucketed scatter:
//  route_k: coarse multisplit into 196 buckets (dst>>9) via LDS histogram +
//    per-(block,bucket) contiguous runs in tmp (~21-edge runs, ~1.4x ampl).
//    Payload: {src, eid | dst_local<<21}.
//  fine_k: one block per bucket; per-node cursors in LDS (init from
//    row_ptr); final epk[p] writes all come from ONE block -> one L2 ->
//    lines merge -> ~13MB actual writes.
// Everything else identical to r20 (edge_emb gather, conv sequential e16s,
// edge-balanced conv units, node_emb2, BN-in-proj, matvec2, pool_bn).

#define N_NODES 100000
#define N_EDGES 1600000
#define NUM_GRAPHS 4096
#define BK_SH 9
#define NBK ((N_NODES + 511) >> 9)     // 196 buckets of 512 nodes
#define CHUNK 4096                     // edges per route_k block

typedef unsigned short u16;
typedef unsigned int u32;
typedef _Float16 h2 __attribute__((ext_vector_type(2)));

#if defined(__has_builtin)
#if __has_builtin(__builtin_amdgcn_fdot2)
#define DOT2(a, b, c) __builtin_amdgcn_fdot2((a), (b), (c), false)
#endif
#endif
#ifndef DOT2
#define DOT2(a, b, c) ((c) + (float)(a).x * (float)(b).x + (float)(a).y * (float)(b).y)
#endif

__device__ __forceinline__ float b2f(u16 u) { union { u32 i; float f; } c; c.i = ((u32)u) << 16; return c.f; }
__device__ __forceinline__ float b2f_lo(u32 u) { union { u32 i; float f; } c; c.i = u << 16; return c.f; }
__device__ __forceinline__ float b2f_hi(u32 u) { union { u32 i; float f; } c; c.i = u & 0xffff0000u; return c.f; }
__device__ __forceinline__ u16 f2b(float f) {
    __hip_bfloat16 h = __float2bfloat16(f);
    return *reinterpret_cast<u16*>(&h);
}

template <int CPL>
__device__ __forceinline__ void ld_bf16(const u16* base, float out[CPL]) {
    if constexpr (CPL == 1) {
        out[0] = b2f(*base);
    } else {
        u32 v = *(const u32*)base;
        out[0] = b2f_lo(v); out[1] = b2f_hi(v);
    }
}
template <int CPL>
__device__ __forceinline__ void ld_f32(const float* base, float out[CPL]) {
    if constexpr (CPL == 1) {
        out[0] = *base;
    } else {
        float2 v = *(const float2*)base;
        out[0] = v.x; out[1] = v.y;
    }
}

// ---------------- CSR build ----------------
__global__ __launch_bounds__(256) void hist_k(const int* __restrict__ dst, int* __restrict__ hist) {
    int e = blockIdx.x * 256 + threadIdx.x;
    if (e < N_EDGES) atomicAdd(&hist[dst[e]], 1);
}

__global__ __launch_bounds__(256) void scan_part_k(const int* __restrict__ hist,
        int* __restrict__ excl, int* __restrict__ bsum) {
    __shared__ int sm[256];
    int t = threadIdx.x, b = blockIdx.x;
    int base = b * 1024 + t * 4;
    int v0 = (base + 0 < N_NODES) ? hist[base + 0] : 0;
    int v1 = (base + 1 < N_NODES) ? hist[base + 1] : 0;
    int v2 = (base + 2 < N_NODES) ? hist[base + 2] : 0;
    int v3 = (base + 3 < N_NODES) ? hist[base + 3] : 0;
    int tsum = v0 + v1 + v2 + v3;
    sm[t] = tsum;
    __syncthreads();
    for (int o = 1; o < 256; o <<= 1) {
        int x = (t >= o) ? sm[t - o] : 0;
        __syncthreads();
        sm[t] += x;
        __syncthreads();
    }
    int texcl = sm[t] - tsum;
    if (base + 0 < N_NODES) excl[base + 0] = texcl;
    if (base + 1 < N_NODES) excl[base + 1] = texcl + v0;
    if (base + 2 < N_NODES) excl[base + 2] = texcl + v0 + v1;
    if (base + 3 < N_NODES) excl[base + 3] = texcl + v0 + v1 + v2;
    if (t == 255) bsum[b] = sm[255];
}

__global__ __launch_bounds__(256) void scan_top_k(int* __restrict__ bsum, int* __restrict__ boff,
        int nb, int* __restrict__ row_ptr_last) {
    __shared__ int sm[256];
    int t = threadIdx.x;
    int v = (t < nb) ? bsum[t] : 0;
    sm[t] = v;
    __syncthreads();
    for (int o = 1; o < 256; o <<= 1) {
        int x = (t >= o) ? sm[t - o] : 0;
        __syncthreads();
        sm[t] += x;
        __syncthreads();
    }
    if (t < nb) boff[t] = sm[t] - v;
    if (t == 0) *row_ptr_last = sm[255];
}

__global__ __launch_bounds__(256) void scan_add_k(int* __restrict__ excl, const int* __restrict__ boff,
        int* __restrict__ row_ptr) {
    int i = blockIdx.x * 256 + threadIdx.x;
    if (i >= N_NODES) return;
    row_ptr[i] = excl[i] + boff[i >> 10];
}

// bucket cursor init: bcur[b] = row_ptr[b*512]
__global__ __launch_bounds__(256) void bucketcur_k(const int* __restrict__ row_ptr, int* __restrict__ bcur) {
    int b = blockIdx.x * 256 + threadIdx.x;
    if (b < NBK) bcur[b] = row_ptr[b << BK_SH];
}

// pass 1: coarse multisplit into buckets; contiguous runs per (block,bucket)
__global__ __launch_bounds__(256) void route_k(const int* __restrict__ src, const int* __restrict__ dst,
        int* __restrict__ bcur, int2* __restrict__ tmp) {
    __shared__ int hcnt[NBK];
    __shared__ int hbase[NBK];
    const int t = threadIdx.x;
    const int e0 = blockIdx.x * CHUNK;
    const int e1 = (e0 + CHUNK < N_EDGES) ? e0 + CHUNK : N_EDGES;
    for (int i = t; i < NBK; i += 256) hcnt[i] = 0;
    __syncthreads();
    for (int e = e0 + t; e < e1; e += 256)
        atomicAdd(&hcnt[dst[e] >> BK_SH], 1);
    __syncthreads();
    for (int i = t; i < NBK; i += 256) {
        int c = hcnt[i];
        hbase[i] = (c > 0) ? atomicAdd(&bcur[i], c) : 0;
        hcnt[i] = 0;
    }
    __syncthreads();
    for (int e = e0 + t; e < e1; e += 256) {
        int d = dst[e];
        int b = d >> BK_SH;
        int r = atomicAdd(&hcnt[b], 1);
        int2 q;
        q.x = src[e];
        q.y = e | ((d & 511) << 21);          // eid (21b) | dst_local (9b)
        tmp[hbase[b] + r] = q;
    }
}

// pass 2: fine scatter within bucket; one block per bucket, cursors in LDS
__global__ __launch_bounds__(256) void fine_k(const int* __restrict__ row_ptr,
        const int2* __restrict__ tmp, int2* __restrict__ epk) {
    __shared__ int cur[512];
    const int t = threadIdx.x;
    const int b = blockIdx.x;
    const int n0 = b << BK_SH;
    for (int i = t; i < 512; i += 256) {
        int n = n0 + i;
        cur[i] = row_ptr[(n < N_NODES) ? n : N_NODES];
    }
    __syncthreads();
    const int nEnd = (n0 + 512 < N_NODES) ? n0 + 512 : N_NODES;
    const int p0 = row_ptr[n0], p1 = row_ptr[nEnd];
    for (int i = p0 + t; i < p1; i += 256) {
        int2 q = tmp[i];
        int dl = (q.y >> 21) & 511;
        int pos = atomicAdd(&cur[dl], 1);
        int2 o;
        o.x = q.x;
        o.y = q.y & 0x1FFFFF;                 // restore eid
        epk[pos] = o;
    }
}

// edge-balanced node partition: sn[u] = lower_bound(row_ptr, 64*u)
__global__ __launch_bounds__(256) void ubound_k(const int* __restrict__ row_ptr, int* __restrict__ sn) {
    int u = blockIdx.x * 256 + threadIdx.x;
    if (u > 25000) return;
    if (u == 25000) { sn[u] = N_NODES; return; }
    int target = u * 64;
    int lo = 0, hi = N_NODES;
    while (lo < hi) {
        int mid = (lo + hi) >> 1;
        if (row_ptr[mid] >= target) hi = mid; else lo = mid + 1;
    }
    sn[u] = lo;
}

// ---------------- edge embedding: CSR-order output, ea gathered by eid ----
__global__ __launch_bounds__(256) void edge_emb_k(const float* __restrict__ ea,
        const float* __restrict__ We, const float* __restrict__ be,
        const int2* __restrict__ epk, _Float16* __restrict__ e16s) {
    int idx = blockIdx.x * 256 + threadIdx.x;       // E*16 threads exactly
    int p = idx >> 4, k = idx & 15;
    int e = epk[p].y;
    float4 a0 = *(const float4*)(ea + (size_t)e * 8);
    float4 a1 = *(const float4*)(ea + (size_t)e * 8 + 4);
    float acc = be[k];
    acc += a0.x * We[0 * 16 + k];
    acc += a0.y * We[1 * 16 + k];
    acc += a0.z * We[2 * 16 + k];
    acc += a0.w * We[3 * 16 + k];
    acc += a1.x * We[4 * 16 + k];
    acc += a1.y * We[5 * 16 + k];
    acc += a1.z * We[6 * 16 + k];
    acc += a1.w * We[7 * 16 + k];
    e16s[(size_t)idx] = (_Float16)fmaxf(acc, 0.f);
}

// ---------------- node embedding: proj-pattern ----------------
__global__ __launch_bounds__(256) void node_emb2_k(const float* __restrict__ x,
        const float* __restrict__ Wn, const float* __restrict__ bn_, float* __restrict__ h) {
    constexpr int C = 64, F = 32, TILE = 64;     // 4 node groups x 16 nodes
    __shared__ float xs[TILE * F];               // 8 KB
    const int t = threadIdx.x;
    const int grp = t / C;
    const int c = t % C;
    float w[F];
#pragma unroll
    for (int k = 0; k < F; ++k) w[k] = Wn[(size_t)k * 64 + c];
    const float bias = bn_[c];
    const float4* xsrc = (const float4*)x;
    float4* xs4 = (float4*)xs;

    for (int v0 = blockIdx.x * TILE; v0 < N_NODES; v0 += gridDim.x * TILE) {
        __syncthreads();
        for (int i = t; i < TILE * F / 4; i += 256) {   // 512 float4, 2/thread
            int vv = v0 + (i * 4) / F;
            float4 val;
            if (vv < N_NODES) val = xsrc[(size_t)v0 * (F / 4) + i];
            else { val.x = val.y = val.z = val.w = 0.f; }
            xs4[i] = val;
        }
        __syncthreads();
        const int base = grp * 16;
        const int nmax = (N_NODES - v0 - base >= 16) ? 16
                        : (N_NODES - v0 - base > 0 ? N_NODES - v0 - base : 0);
        for (int n = 0; n < nmax; ++n) {
            const int v = v0 + base + n;
            const float4* xr4 = (const float4*)&xs[(base + n) * F];
            float a0 = bias, a1 = 0.f, a2 = 0.f, a3 = 0.f;
#pragma unroll
            for (int k4 = 0; k4 < F / 4; ++k4) {
                float4 hv = xr4[k4];
                a0 += hv.x * w[4 * k4 + 0];
                a1 += hv.y * w[4 * k4 + 1];
                a2 += hv.z * w[4 * k4 + 2];
                a3 += hv.w * w[4 * k4 + 3];
            }
            h[(size_t)v * 64 + c] = fmaxf((a0 + a1) + (a2 + a3), 0.f);
        }
    }
}

// ---------------- projections: Pd fp32, Ps bf16; optional fused BN+relu ----
template <int F, int H, bool BN>
__global__ __launch_bounds__(256) void proj_k(const float* __restrict__ h,
        const float* __restrict__ Wa, const float* __restrict__ ba,
        const float* __restrict__ stats, const float* __restrict__ g, const float* __restrict__ beta,
        float* __restrict__ Pd, u16* __restrict__ Ps) {
    constexpr int C2 = 2 * H;
    constexpr int NPB = 256 / C2;
    constexpr int TILE = 16 * NPB;
    __shared__ float hs[TILE][F];
    __shared__ float sc[BN ? F : 1];
    __shared__ float shv[BN ? F : 1];
    const int t = threadIdx.x;
    if constexpr (BN) {
        if (t < F) {
            const float invN = 1.0f / (float)N_NODES;
            float mu = stats[t] * invN;
            float ex2 = stats[F + t] * invN;
            float var = fmaxf(ex2 - mu * mu, 0.f);
            float rs = rsqrtf(var + 1e-5f);
            float scale = rs * g[t];
            sc[t] = scale;
            shv[t] = beta[t] - mu * scale;
        }
    }
    const int grp = t / C2;
    const int c = t % C2;
    const bool is_src = (c >= H);
    const int cc = is_src ? (c - H) : c;
    float w[F];
    const float* wcol = Wa + (size_t)(is_src ? F : 0) * H + cc;
#pragma unroll
    for (int k = 0; k < F; ++k) w[k] = wcol[(size_t)k * H];
    const float bias = is_src ? 0.f : ba[cc];

    for (int v0 = blockIdx.x * TILE; v0 < N_NODES; v0 += gridDim.x * TILE) {
        __syncthreads();
        for (int i = t; i < TILE * F; i += 256) {
            int vv = v0 + i / F;
            float val = (vv < N_NODES) ? h[(size_t)vv * F + (i % F)] : 0.f;
            if constexpr (BN) val = fmaxf(val * sc[i % F] + shv[i % F], 0.f);
            hs[i / F][i % F] = val;
        }
        __syncthreads();
        const int base = grp * 16;
        const int nmax = (N_NODES - v0 - base >= 16) ? 16
                        : (N_NODES - v0 - base > 0 ? N_NODES - v0 - base : 0);
#pragma unroll 2
        for (int n = 0; n < nmax; ++n) {
            const int v = v0 + base + n;
            const float4* hr4 = (const float4*)hs[base + n];
            float a0 = bias, a1 = 0.f, a2 = 0.f, a3 = 0.f;
#pragma unroll
            for (int k4 = 0; k4 < F / 4; ++k4) {
                float4 hv = hr4[k4];
                a0 += hv.x * w[4 * k4 + 0];
                a1 += hv.y * w[4 * k4 + 1];
                a2 += hv.z * w[4 * k4 + 2];
                a3 += hv.w * w[4 * k4 + 3];
            }
            float acc = (a0 + a1) + (a2 + a3);
            if (is_src) Ps[(size_t)v * H + cc] = f2b(acc);
            else        Pd[(size_t)v * H + cc] = acc;
        }
    }
}

// ---------------- fused conv: edge-balanced units, sequential e16s ---------
template <int H>
__global__ __launch_bounds__(256) void conv_k(
        const int* __restrict__ sn, const int* __restrict__ row_ptr,
        const int2* __restrict__ epk, const _Float16* __restrict__ e16s,
        float* __restrict__ Pd, const u16* __restrict__ Ps,
        const float* __restrict__ Wae) {
    constexpr int SL = (H >= 64) ? 64 : 32;   // lanes per node
    constexpr int NPW = 64 / SL;              // units per wave
    constexpr int CPL = H / SL;               // channels per lane
    const int wave = threadIdx.x >> 6, lane = threadIdx.x & 63;
    const int sub = lane / SL;
    const int sl = lane % SL;
    const int c0 = sl * CPL;
    h2 w2h[8][CPL];
#pragma unroll
    for (int k2 = 0; k2 < 8; ++k2)
#pragma unroll
        for (int j = 0; j < CPL; ++j) {
            h2 t;
            t.x = (_Float16)Wae[(2 * k2) * H + c0 + j];
            t.y = (_Float16)Wae[(2 * k2 + 1) * H + c0 + j];
            w2h[k2][j] = t;
        }

    const int uid = (blockIdx.x * 4 + wave) * NPW + sub;
    const int vbeg = sn[uid], vend = sn[uid + 1];

    for (int v = vbeg; v < vend; ++v) {
        const int vv = (SL == 64) ? __builtin_amdgcn_readfirstlane(v) : v;
        float pd[CPL], acc[CPL];
        ld_f32<CPL>(&Pd[(size_t)vv * H + c0], pd);
#pragma unroll
        for (int j = 0; j < CPL; ++j) acc[j] = 0.f;
        const int p0 = row_ptr[vv], p1 = row_ptr[vv + 1];
        const int deg = p1 - p0;

        auto edge = [&](uint4 ra, uint4 rb, const float ps[CPL]) {
            union { u32 u; h2 h; } cv;
            h2 ev[8];
            cv.u = ra.x; ev[0] = cv.h; cv.u = ra.y; ev[1] = cv.h;
            cv.u = ra.z; ev[2] = cv.h; cv.u = ra.w; ev[3] = cv.h;
            cv.u = rb.x; ev[4] = cv.h; cv.u = rb.y; ev[5] = cv.h;
            cv.u = rb.z; ev[6] = cv.h; cv.u = rb.w; ev[7] = cv.h;
            float z[CPL];
#pragma unroll
            for (int j = 0; j < CPL; ++j) z[j] = pd[j] + ps[j];
#pragma unroll
            for (int k2 = 0; k2 < 8; ++k2)
#pragma unroll
                for (int j = 0; j < CPL; ++j) z[j] = DOT2(ev[k2], w2h[k2][j], z[j]);
#pragma unroll
            for (int j = 0; j < CPL; ++j) acc[j] += fmaxf(z[j], 0.f);
        };

        int p = p0;
        for (; p + 3 < p1; p += 4) {
            int2 q0 = epk[p], q1 = epk[p + 1], q2 = epk[p + 2], q3 = epk[p + 3];
            const uint4* e0 = (const uint4*)(e16s + (size_t)p * 16);
            uint4 a0 = e0[0], a1 = e0[1];
            uint4 b0 = e0[2], b1 = e0[3];
            uint4 g0 = e0[4], g1 = e0[5];
            uint4 d0 = e0[6], d1 = e0[7];
            float ps0[CPL], ps1[CPL], ps2[CPL], ps3[CPL];
            ld_bf16<CPL>(&Ps[(size_t)q0.x * H + c0], ps0);
            ld_bf16<CPL>(&Ps[(size_t)q1.x * H + c0], ps1);
            ld_bf16<CPL>(&Ps[(size_t)q2.x * H + c0], ps2);
            ld_bf16<CPL>(&Ps[(size_t)q3.x * H + c0], ps3);
            edge(a0, a1, ps0);
            edge(b0, b1, ps1);
            edge(g0, g1, ps2);
            edge(d0, d1, ps3);
        }
        for (; p < p1; ++p) {
            int2 q0 = epk[p];
            const uint4* e0 = (const uint4*)(e16s + (size_t)p * 16);
            uint4 a0 = e0[0], a1 = e0[1];
            float ps0[CPL];
            ld_bf16<CPL>(&Ps[(size_t)q0.x * H + c0], ps0);
            edge(a0, a1, ps0);
        }

        const float invd = (deg > 0) ? 1.f / (float)deg : 0.f;
        if constexpr (CPL == 2) {
            float2 o; o.x = acc[0] * invd; o.y = acc[1] * invd;
            *(float2*)&Pd[(size_t)vv * H + c0] = o;
        } else {
            Pd[(size_t)vv * H + c0] = acc[0] * invd;
        }
    }
}

// ---------------- y = m @ Wb + bb (deg>0 mask) + fused BN stats ----------
template <int H, int Fo>
__global__ __launch_bounds__(256) void matvec2_k(const float* __restrict__ m,
        const int* __restrict__ row_ptr,
        const float* __restrict__ Wb, const float* __restrict__ bb,
        float* __restrict__ y, float* __restrict__ stats) {
    constexpr int FoC = (Fo < 32) ? Fo : 32;  // channels per wave: 32/32/16
    constexpr int CG = Fo / FoC;              // channel groups: 2/1/1
    constexpr int NPW = 32 / FoC;             // node subs per half-wave: 1/1/2
    constexpr int NG = 4 / CG;                // node groups (waves): 2/4/4
    constexpr int SLOTS = NG * NPW;           // node slots per pass: 2/4/8
    constexpr int KH = H / 2;                 // k per lane: 64/32/16
    constexpr int TILE = 4096 / H;            // nodes per tile: 32/64/128
    constexpr int J = TILE / SLOTS;           // 16 for all shapes

    __shared__ float hs[TILE * H];            // 16 KB
    __shared__ int ptile[TILE + 1];
    __shared__ float sh[2 * Fo];

    const int t = threadIdx.x;
    const int wave = t >> 6, lane = t & 63;
    const int kh = lane >> 5;
    const int r = lane & 31;
    const int c_lo = r % FoC;
    const int s = r / FoC;
    const int cg = wave % CG;
    const int ng = wave / CG;
    const int c = cg * FoC + c_lo;
    const int slot = ng * NPW + s;

    for (int i = t; i < 2 * Fo; i += 256) sh[i] = 0.f;

    float w[KH];
#pragma unroll
    for (int k = 0; k < KH; ++k) w[k] = Wb[(size_t)(kh * KH + k) * Fo + c];
    const float bias = bb[c];
    float s1 = 0.f, s2 = 0.f;

    const float4* msrc = (const float4*)m;
    float4* hs4 = (float4*)hs;

    for (int v0 = blockIdx.x * TILE; v0 < N_NODES; v0 += gridDim.x * TILE) {
        __syncthreads();
#pragma unroll
        for (int q = t; q < 1024; q += 256) {
            int node = (q * 4) / H;
            float4 val;
            if (v0 + node < N_NODES) val = msrc[(size_t)v0 * (H / 4) + q];
            else { val.x = val.y = val.z = val.w = 0.f; }
            hs4[q] = val;
        }
        for (int i = t; i <= TILE; i += 256) {
            int v = v0 + i;
            ptile[i] = row_ptr[v < N_NODES ? v : N_NODES];
        }
        __syncthreads();

        for (int j = 0; j < J; ++j) {
            const int n = slot + j * SLOTS;
            const int v = v0 + n;
            const float4* hr4 = (const float4*)&hs[n * H + kh * KH];
            float a0 = 0.f, a1 = 0.f, a2 = 0.f, a3 = 0.f;
#pragma unroll
            for (int k4 = 0; k4 < KH / 4; ++k4) {
                float4 hv = hr4[k4];
                a0 += hv.x * w[4 * k4 + 0];
                a1 += hv.y * w[4 * k4 + 1];
                a2 += hv.z * w[4 * k4 + 2];
                a3 += hv.w * w[4 * k4 + 3];
            }
            float half = (a0 + a1) + (a2 + a3);
            float total = half + __shfl_xor(half, 32) + bias;
            if (kh == 0 && v < N_NODES) {
                const int deg = ptile[n + 1] - ptile[n];
                float val = (deg > 0) ? total : 0.f;
                y[(size_t)v * Fo + c] = val;
                s1 += val; s2 += val * val;
            }
        }
    }

    __syncthreads();
    if (kh == 0) {
        atomicAdd(&sh[c], s1);
        atomicAdd(&sh[Fo + c], s2);
    }
    __syncthreads();
    if (t < 2 * Fo) atomicAdd(&stats[t], sh[t]);
}

// ---------------- pooling (fused BN3+relu) & head ----------------
__global__ __launch_bounds__(256) void pool_bn_k(const float* __restrict__ y,
        const float* __restrict__ stats, const float* __restrict__ g, const float* __restrict__ beta,
        const int* __restrict__ batch, float* __restrict__ pool, int* __restrict__ gcnt) {
    int idx = blockIdx.x * 256 + threadIdx.x;
    if (idx >= N_NODES * 16) return;
    int v = idx >> 4, c = idx & 15;
    const float invN = 1.0f / (float)N_NODES;
    float mu = stats[c] * invN;
    float ex2 = stats[16 + c] * invN;
    float var = fmaxf(ex2 - mu * mu, 0.f);
    float rs = rsqrtf(var + 1e-5f);
    float val = fmaxf((y[idx] - mu) * rs * g[c] + beta[c], 0.f);
    int b = batch[v];
    atomicAdd(&pool[b * 16 + c], val);
    if (c == 0) atomicAdd(&gcnt[b], 1);
}

__global__ __launch_bounds__(256) void out_k(const float* __restrict__ pool,
        const int* __restrict__ gcnt, const float* __restrict__ Wfc,
        const float* __restrict__ bfc, float* __restrict__ out) {
    int idx = blockIdx.x * 256 + threadIdx.x;
    if (idx >= NUM_GRAPHS * 12) return;
    int g = idx / 12, o = idx % 12;
    int cnt = gcnt[g];
    float inv = 1.0f / (float)(cnt > 0 ? cnt : 1);
    float acc = bfc[o];
#pragma unroll
    for (int k = 0; k < 16; ++k) acc += pool[g * 16 + k] * inv * Wfc[k * 12 + o];
    out[idx] = 1.0f / (1.0f + expf(-acc));
}

extern "C" void kernel_launch(void* const* d_in, const int* in_sizes, int n_in,
                              void* d_out, int out_size, void* d_ws, size_t ws_size,
                              hipStream_t stream) {
    const size_t N = N_NODES, E = N_EDGES, G = NUM_GRAPHS;
    const float* x = (const float*)d_in[0];
    const float* ea = (const float*)d_in[1];
    const int* ei = (const int*)d_in[2];
    const int* srcv = ei;
    const int* dstv = ei + E;
    const int* batch = (const int*)d_in[3];
    const float* Wn = (const float*)d_in[5];  const float* bn_ = (const float*)d_in[6];
    const float* We = (const float*)d_in[7];  const float* be_ = (const float*)d_in[8];
    const float* W1a = (const float*)d_in[9]; const float* b1a = (const float*)d_in[10];
    const float* W1b = (const float*)d_in[11]; const float* b1b = (const float*)d_in[12];
    const float* W2a = (const float*)d_in[13]; const float* b2a = (const float*)d_in[14];
    const float* W2b = (const float*)d_in[15]; const float* b2b = (const float*)d_in[16];
    const float* W3a = (const float*)d_in[17]; const float* b3a = (const float*)d_in[18];
    const float* W3b = (const float*)d_in[19]; const float* b3b = (const float*)d_in[20];
    const float* g1 = (const float*)d_in[21]; const float* be1 = (const float*)d_in[22];
    const float* g2 = (const float*)d_in[23]; const float* be2 = (const float*)d_in[24];
    const float* g3 = (const float*)d_in[25]; const float* be3 = (const float*)d_in[26];
    const float* Wfc = (const float*)d_in[27]; const float* bfc = (const float*)d_in[28];

    char* base = (char*)d_ws;
    size_t off = 0;
    auto take = [&](size_t bytes) { size_t o = off; off += (bytes + 255) & ~(size_t)255; return o; };
    int* hist = (int*)(base + take(N * 4));
    int* excl = (int*)(base + take(N * 4));
    int* row_ptr = (int*)(base + take((N + 1) * 4));
    int* bsum = (int*)(base + take(256 * 4));
    int* boff = (int*)(base + take(256 * 4));
    int* bcur = (int*)(base + take(256 * 4));
    int* sn = (int*)(base + take(25001 * 4));
    int2* epk = (int2*)(base + take(E * 8));
    int2* tmp = (int2*)(base + take(E * 8));
    float* hbuf = (float*)(base + take(N * 64 * 4));
    float* Pd = (float*)(base + take(N * 128 * 4));
    u16* Ps = (u16*)(base + take(N * 128 * 2));
    _Float16* e16s = (_Float16*)(base + take(E * 16 * 2));
    float* stats = (float*)(base + take(256 * 4));
    float* pool = (float*)(base + take(G * 16 * 4));
    int* gcnt = (int*)(base + take(G * 4));
    if (off > ws_size) {
        fprintf(stderr, "kernel_launch: ws too small: need %zu have %zu\n", off, ws_size);
        return;
    }

    const int NB = (N_NODES + 1023) / 1024;

    // CSR build: hist/scan -> row_ptr; two-pass bucketed scatter -> epk
    hipMemsetAsync(hist, 0, N * 4, stream);
    hist_k<<<dim3((E + 255) / 256), dim3(256), 0, stream>>>(dstv, hist);
    scan_part_k<<<dim3(NB), dim3(256), 0, stream>>>(hist, excl, bsum);
    scan_top_k<<<dim3(1), dim3(256), 0, stream>>>(bsum, boff, NB, &row_ptr[N_NODES]);
    scan_add_k<<<dim3((N + 255) / 256), dim3(256), 0, stream>>>(excl, boff, row_ptr);
    bucketcur_k<<<dim3(1), dim3(256), 0, stream>>>(row_ptr, bcur);
    route_k<<<dim3((N_EDGES + CHUNK - 1) / CHUNK), dim3(256), 0, stream>>>(srcv, dstv, bcur, tmp);
    fine_k<<<dim3(NBK), dim3(256), 0, stream>>>(row_ptr, tmp, epk);
    ubound_k<<<dim3((25001 + 255) / 256), dim3(256), 0, stream>>>(row_ptr, sn);

    // embeddings: e16s in CSR order (coalesced write, random L3 ea reads)
    edge_emb_k<<<dim3(E * 16 / 256), dim3(256), 0, stream>>>(ea, We, be_, epk, e16s);
    node_emb2_k<<<dim3(1563), dim3(256), 0, stream>>>(x, Wn, bn_, hbuf);

    // conv1: F=64, H=128, Fo=64  (no BN on h)
    proj_k<64, 128, false><<<dim3(6250), dim3(256), 0, stream>>>(hbuf, W1a, b1a, nullptr, nullptr, nullptr, Pd, Ps);
    conv_k<128><<<dim3(6250), dim3(256), 0, stream>>>(sn, row_ptr, epk, e16s, Pd, Ps, W1a + 128 * 128);
    hipMemsetAsync(stats, 0, 256 * 4, stream);
    matvec2_k<128, 64><<<dim3(1024), dim3(256), 0, stream>>>(Pd, row_ptr, W1b, b1b, hbuf, stats);

    // conv2: F=64, H=64, Fo=32  (BN1 fused into proj staging)
    proj_k<64, 64, true><<<dim3(3125), dim3(256), 0, stream>>>(hbuf, W2a, b2a, stats, g1, be1, Pd, Ps);
    conv_k<64><<<dim3(6250), dim3(256), 0, stream>>>(sn, row_ptr, epk, e16s, Pd, Ps, W2a + 128 * 64);
    hipMemsetAsync(stats, 0, 256 * 4, stream);
    matvec2_k<64, 32><<<dim3(1024), dim3(256), 0, stream>>>(Pd, row_ptr, W2b, b2b, hbuf, stats);

    // conv3: F=32, H=32, Fo=16  (BN2 fused into proj staging)
    proj_k<32, 32, true><<<dim3(1563), dim3(256), 0, stream>>>(hbuf, W3a, b3a, stats, g2, be2, Pd, Ps);
    conv_k<32><<<dim3(3125), dim3(256), 0, stream>>>(sn, row_ptr, epk, e16s, Pd, Ps, W3a + 64 * 32);
    hipMemsetAsync(stats, 0, 256 * 4, stream);
    matvec2_k<32, 16><<<dim3(1024), dim3(256), 0, stream>>>(Pd, row_ptr, W3b, b3b, hbuf, stats);

    // pool (BN3+relu fused) + head
    hipMemsetAsync(pool, 0, G * 16 * 4, stream);
    hipMemsetAsync(gcnt, 0, G * 4, stream);
    pool_bn_k<<<dim3((N * 16 + 255) / 256), dim3(256), 0, stream>>>(hbuf, stats, g3, be3, batch, pool, gcnt);
    out_k<<<dim3((G * 12 + 255) / 256), dim3(256), 0, stream>>>(pool, gcnt, Wfc, bfc, (float*)d_out);
}